// Round 10
// baseline (508.514 us; speedup 1.0000x reference)
//
#include <hip/hip_runtime.h>
#include <math.h>

#define N_ROWS 16384
#define DMODEL 1024
#define DFF    4096

typedef _Float16 f16;
typedef __attribute__((ext_vector_type(4))) _Float16 f16x4;
typedef __attribute__((ext_vector_type(8))) _Float16 f16x8;
typedef __attribute__((ext_vector_type(4))) float f32x4;

__device__ inline void async_ld16(const f16* g, f16* l) {
  __builtin_amdgcn_global_load_lds(
      (__attribute__((address_space(1))) void*)(g),
      (__attribute__((address_space(3))) void*)(l),
      16, 0, 0);
}

// tanh via hw v_exp_f32: ~5 VALU ops vs libm tanhf's branchy ~40.
__device__ inline float fast_tanh(float x) {
  float t = __expf(2.0f * x);
  return 1.0f - 2.0f / (t + 1.0f);
}

// Merged pre-pass: casts batch/W1/W2 f32->f16 AND zeroes the row-accumulator.
__global__ void cast_and_zero(const float* __restrict__ batch, f16* __restrict__ batch_h,
                              const float* __restrict__ W1, f16* __restrict__ W1_h,
                              const float* __restrict__ W2, f16* __restrict__ W2_h,
                              float* __restrict__ rowacc) {
  const size_t nb = (size_t)N_ROWS * DMODEL;
  const size_t nw = (size_t)DFF * DMODEL;
  size_t off = ((size_t)blockIdx.x * blockDim.x + threadIdx.x) * 8;
  const float* src; f16* dst; size_t o;
  if (off < nb) { src = batch; dst = batch_h; o = off; }
  else if (off < nb + nw) { src = W1; dst = W1_h; o = off - nb; }
  else if (off < nb + 2 * nw) { src = W2; dst = W2_h; o = off - nb - nw; }
  else {  // zero 8 floats of rowacc
    size_t z = off - nb - 2 * nw;
    float4 zz = {0.f, 0.f, 0.f, 0.f};
    ((float4*)(rowacc + z))[0] = zz;
    ((float4*)(rowacc + z))[1] = zz;
    return;
  }
  float4 v0 = ((const float4*)(src + o))[0];
  float4 v1 = ((const float4*)(src + o))[1];
  f16x8 h = { (f16)v0.x, (f16)v0.y, (f16)v0.z, (f16)v0.w,
              (f16)v1.x, (f16)v1.y, (f16)v1.z, (f16)v1.w };
  *(f16x8*)(dst + o) = h;
}

#define BARRIER() __builtin_amdgcn_s_barrier()
#define WAIT_VMCNT(n) asm volatile("s_waitcnt vmcnt(" #n ")")

// ---------------------------------------------------------------------------
// GEMM core = r6 structure (2-phase counted-vmcnt, 0 bank conflicts), byte-
// identical K-loop. r9 post-mortem: per-GEMM time == MFMA(66us) + LDS-read
// (45us) + memory(60us) ADDED -> the mem term is the attackable one:
// FETCH 270MB vs 40MB ideal. Two locality fixes this round:
//  (1) XCD BAND mapping (replaces the old swizzle, which made each XCD's 32
//      resident blocks touch ALL 64 A row-panels -> 32MB working set on a
//      4MB L2). Now XCD k = lin&7 owns row-tiles [8k,8k+8): resident working
//      set = 8 A-panels = 4MB (fits L2) + 4 B-panels. Bijective: nbx=64,
//      nwg%8==0 for both GEMMs.
//  (2) Nontemporal C stores (GEMM1): the 128MB C stream was evicting A/B
//      panels from L2 continuously.
//
// FUSE=false: C[M,Nc] = tanh(A@B^T + bias) -> f16 (GEMM1).
// FUSE=true : no C write; per-row atomicAdd of sum_col tanh(acc+b)*batchf
//             into rowacc (GEMM2 + rowdot fused).
// ---------------------------------------------------------------------------
template <int K, bool FUSE>
__global__ __launch_bounds__(512, 2)
void gemm256_tanh(const f16* __restrict__ A, const f16* __restrict__ B,
                  const float* __restrict__ bias, f16* __restrict__ C, int Nc,
                  float* __restrict__ rowacc, const float* __restrict__ batchf) {
  extern __shared__ __align__(16) char smem[];
  f16* lds = (f16*)smem;

  const int tid  = threadIdx.x;
  const int lane = tid & 63;
  const int wave = tid >> 6;
  const int wm = (wave >> 2) * 128;
  const int wn = (wave & 3) * 64;
  const int fr = lane & 15;
  const int g  = lane >> 4;

  // XCD band mapping (r10): xcd = lin&7 (round-robin dispatch, m09); band of
  // nbx/8 row-tiles per XCD; col-major sweep within the band.
  const int nbx = gridDim.x;
  const int lin = blockIdx.y * nbx + blockIdx.x;
  const int xcd = lin & 7;
  const int c   = lin >> 3;
  const int rband = nbx >> 3;
  const size_t row0 = (size_t)(xcd * rband + (c % rband)) * 256;
  const size_t col0 = (size_t)(c / rband) * 256;

  // Staging: per unit (kk-half of one operand, 256x32 f16 = 16KB), thread
  // covers 16B slots s = l*512+tid; source chunk pre-swizzled (rule #21):
  // schunk = (s&3) ^ ((s>>3)&3).
  const int schunk = (tid & 3) ^ ((tid >> 3) & 3);
  const f16* Asrc[2]; const f16* Bsrc[2];
  const int sdst0 = tid * 8;
  const int sdst1 = 4096 + tid * 8;
  Asrc[0] = A + (row0 + (tid >> 2)) * (size_t)K + schunk * 8;
  Asrc[1] = A + (row0 + 128 + (tid >> 2)) * (size_t)K + schunk * 8;
  Bsrc[0] = B + (col0 + (tid >> 2)) * (size_t)K + schunk * 8;
  Bsrc[1] = B + (col0 + 128 + (tid >> 2)) * (size_t)K + schunk * 8;

  // LDS f16-offset helpers; read swizzle: slot ^= row bits 1-2 (conflict-free,
  // SQ_LDS_BANK_CONFLICT == 0 measured r3-r9).
  auto aoff = [&](int d, int kk, int m) -> int {
    const int row = wm + m * 16 + fr;
    return d * 32768 + kk * 8192 + row * 32 + (g ^ ((row >> 1) & 3)) * 8;
  };
  auto boff = [&](int d, int kk, int n) -> int {
    const int row = wn + n * 16 + fr;
    return d * 32768 + 16384 + kk * 8192 + row * 32 + (g ^ ((row >> 1) & 3)) * 8;
  };
  auto stage_unit = [&](int j, int db, int kb) {
    const int o = j & 1, kk = j >> 1;
    const int dbase = db * 32768 + o * 16384 + kk * 8192;
    async_ld16((o ? Bsrc[0] : Asrc[0]) + kb + kk * 32, lds + dbase + sdst0);
    async_ld16((o ? Bsrc[1] : Asrc[1]) + kb + kk * 32, lds + dbase + sdst1);
  };

  f32x4 acc[8][4] = {};
  constexpr int NT = K / 64;

  // Prologue: stage tile 0 (units 0..3) into dbuf 0; wait units 0,1.
  stage_unit(0, 0, 0);
  stage_unit(1, 0, 0);
  stage_unit(2, 0, 0);
  stage_unit(3, 0, 0);
  WAIT_VMCNT(4);
  BARRIER();

  for (int t = 0; t < NT; ++t) {
    const int d = t & 1;
    const bool pre = (t + 1) < NT;
    const int kpre = (t + 1) * 64;

    // ---- Phase A: kk0, 32 MFMA ----
    {
      f16x8 bfr[4], afr[8];
#pragma unroll
      for (int n = 0; n < 4; ++n) bfr[n] = *(const f16x8*)(lds + boff(d, 0, n));
#pragma unroll
      for (int i = 0; i < 8; ++i) afr[i] = *(const f16x8*)(lds + aoff(d, 0, i));
      if (pre) { stage_unit(0, d ^ 1, kpre); stage_unit(1, d ^ 1, kpre); }
      BARRIER();
      __builtin_amdgcn_s_setprio(1);
#pragma unroll
      for (int i = 0; i < 8; ++i)
#pragma unroll
        for (int n = 0; n < 4; ++n)
          acc[i][n] = __builtin_amdgcn_mfma_f32_16x16x32_f16(afr[i], bfr[n], acc[i][n], 0, 0, 0);
      __builtin_amdgcn_s_setprio(0);
      if (pre) { WAIT_VMCNT(4); }   // u2,u3(t) landed (in-order retirement)
      else     { WAIT_VMCNT(0); }   // tail drain
      BARRIER();
    }
    // ---- Phase B: kk1, 32 MFMA ----
    {
      f16x8 bfr[4], afr[8];
#pragma unroll
      for (int n = 0; n < 4; ++n) bfr[n] = *(const f16x8*)(lds + boff(d, 1, n));
#pragma unroll
      for (int i = 0; i < 8; ++i) afr[i] = *(const f16x8*)(lds + aoff(d, 1, i));
      if (pre) { stage_unit(2, d ^ 1, kpre); stage_unit(3, d ^ 1, kpre); }
      BARRIER();
      __builtin_amdgcn_s_setprio(1);
#pragma unroll
      for (int i = 0; i < 8; ++i)
#pragma unroll
        for (int n = 0; n < 4; ++n)
          acc[i][n] = __builtin_amdgcn_mfma_f32_16x16x32_f16(afr[i], bfr[n], acc[i][n], 0, 0, 0);
      __builtin_amdgcn_s_setprio(0);
      if (pre) { WAIT_VMCNT(4); }   // u0,u1(t+1) landed
      BARRIER();
    }
  }

  // Epilogue; C/D map: col=lane&15, row=(lane>>4)*4+reg [m89-verified]
  if constexpr (!FUSE) {
#pragma unroll
    for (int m = 0; m < 8; ++m) {
#pragma unroll
      for (int n = 0; n < 4; ++n) {
        const size_t gcol = col0 + wn + n * 16 + fr;
        const float bia = bias[gcol];
        f16* Cp = C + (row0 + wm + m * 16 + g * 4) * (size_t)Nc + gcol;
#pragma unroll
        for (int r = 0; r < 4; ++r)
          __builtin_nontemporal_store((f16)fast_tanh(acc[m][n][r] + bia),
                                      Cp + (size_t)r * Nc);
      }
    }
  } else {
    // Fused rowdot: reduce over fr (16 lanes, shfl_xor 1/2/4/8 within the
    // g-group), then 1 atomicAdd per row per wave.
    float rsum[8][4];
#pragma unroll
    for (int m = 0; m < 8; ++m)
#pragma unroll
      for (int r = 0; r < 4; ++r) rsum[m][r] = 0.f;
#pragma unroll
    for (int m = 0; m < 8; ++m) {
#pragma unroll
      for (int n = 0; n < 4; ++n) {
        const size_t gcol = col0 + wn + n * 16 + fr;
        const float bia = bias[gcol];
        const float* bp = batchf + (row0 + wm + m * 16 + g * 4) * DMODEL + gcol;
#pragma unroll
        for (int r = 0; r < 4; ++r)
          rsum[m][r] += fast_tanh(acc[m][n][r] + bia) * bp[(size_t)r * DMODEL];
      }
    }
#pragma unroll
    for (int m = 0; m < 8; ++m) {
#pragma unroll
      for (int r = 0; r < 4; ++r) {
        float s = rsum[m][r];
        s += __shfl_xor(s, 1, 64);
        s += __shfl_xor(s, 2, 64);
        s += __shfl_xor(s, 4, 64);
        s += __shfl_xor(s, 8, 64);
        if (fr == 0)
          atomicAdd(&rowacc[row0 + wm + m * 16 + g * 4 + r], s);
      }
    }
  }
}

// out[row] = sigmoid(rowacc[row])
__global__ void sigmoid_rows(const float* __restrict__ rowacc, float* __restrict__ out) {
  const int i = blockIdx.x * blockDim.x + threadIdx.x;
  out[i] = 1.0f / (1.0f + __expf(-rowacc[i]));
}

extern "C" void kernel_launch(void* const* d_in, const int* in_sizes, int n_in,
                              void* d_out, int out_size, void* d_ws, size_t ws_size,
                              hipStream_t stream) {
  const float* batch = (const float*)d_in[0];
  const float* W1    = (const float*)d_in[1];
  const float* b1    = (const float*)d_in[2];
  const float* W2    = (const float*)d_in[3];
  const float* b2    = (const float*)d_in[4];
  float* out = (float*)d_out;

  char* ws = (char*)d_ws;
  f16* batch_h  = (f16*)ws;   ws += (size_t)N_ROWS * DMODEL * sizeof(f16);  //  32 MB
  f16* W1_h     = (f16*)ws;   ws += (size_t)DFF * DMODEL * sizeof(f16);     //   8 MB
  f16* W2_h     = (f16*)ws;   ws += (size_t)DMODEL * DFF * sizeof(f16);     //   8 MB
  f16* inner_h  = (f16*)ws;   ws += (size_t)N_ROWS * DFF * sizeof(f16);     // 128 MB
  float* rowacc = (float*)ws; ws += (size_t)N_ROWS * sizeof(float);         //  64 KB

  static bool attr_set = false;
  if (!attr_set) {
    (void)hipFuncSetAttribute((const void*)gemm256_tanh<DMODEL, false>,
                              hipFuncAttributeMaxDynamicSharedMemorySize, 131072);
    (void)hipFuncSetAttribute((const void*)gemm256_tanh<DFF, true>,
                              hipFuncAttributeMaxDynamicSharedMemorySize, 131072);
    attr_set = true;
  }

  // merged casts + rowacc zero
  const size_t nb = (size_t)N_ROWS * DMODEL;
  const size_t nw = (size_t)DFF * DMODEL;
  const int total_thr = (int)((nb + 2 * nw) / 8 + N_ROWS / 8);
  cast_and_zero<<<total_thr / 256, 256, 0, stream>>>(batch, batch_h, W1, W1_h,
                                                     W2, W2_h, rowacc);

  dim3 g1(N_ROWS / 256, DFF / 256);     // (64, 16)
  gemm256_tanh<DMODEL, false><<<g1, 512, 131072, stream>>>(
      batch_h, W1_h, b1, inner_h, DFF, nullptr, nullptr);
  dim3 g2(N_ROWS / 256, DMODEL / 256);  // (64, 4)
  gemm256_tanh<DFF, true><<<g2, 512, 131072, stream>>>(
      inner_h, W2_h, b2, nullptr, DMODEL, rowacc, batch);

  sigmoid_rows<<<N_ROWS / 256, 256, 0, stream>>>(rowacc, out);
}

// Round 11
// 410.559 us; speedup vs baseline: 1.2386x; 1.2386x over previous
//
#include <hip/hip_runtime.h>
#include <math.h>

#define N_ROWS 16384
#define DMODEL 1024
#define DFF    4096

typedef _Float16 f16;
typedef __attribute__((ext_vector_type(4))) _Float16 f16x4;
typedef __attribute__((ext_vector_type(8))) _Float16 f16x8;
typedef __attribute__((ext_vector_type(4))) float f32x4;

__device__ inline void async_ld16(const f16* g, f16* l) {
  __builtin_amdgcn_global_load_lds(
      (__attribute__((address_space(1))) void*)(g),
      (__attribute__((address_space(3))) void*)(l),
      16, 0, 0);
}

// tanh via hw v_exp_f32: ~5 VALU ops vs libm tanhf's branchy ~40.
__device__ inline float fast_tanh(float x) {
  float t = __expf(2.0f * x);
  return 1.0f - 2.0f / (t + 1.0f);
}

// Merged pre-pass: casts batch/W1/W2 f32->f16 AND zeroes the row-accumulator.
__global__ void cast_and_zero(const float* __restrict__ batch, f16* __restrict__ batch_h,
                              const float* __restrict__ W1, f16* __restrict__ W1_h,
                              const float* __restrict__ W2, f16* __restrict__ W2_h,
                              float* __restrict__ rowacc) {
  const size_t nb = (size_t)N_ROWS * DMODEL;
  const size_t nw = (size_t)DFF * DMODEL;
  size_t off = ((size_t)blockIdx.x * blockDim.x + threadIdx.x) * 8;
  const float* src; f16* dst; size_t o;
  if (off < nb) { src = batch; dst = batch_h; o = off; }
  else if (off < nb + nw) { src = W1; dst = W1_h; o = off - nb; }
  else if (off < nb + 2 * nw) { src = W2; dst = W2_h; o = off - nb - nw; }
  else {  // zero 8 floats of rowacc
    size_t z = off - nb - 2 * nw;
    float4 zz = {0.f, 0.f, 0.f, 0.f};
    ((float4*)(rowacc + z))[0] = zz;
    ((float4*)(rowacc + z))[1] = zz;
    return;
  }
  float4 v0 = ((const float4*)(src + o))[0];
  float4 v1 = ((const float4*)(src + o))[1];
  f16x8 h = { (f16)v0.x, (f16)v0.y, (f16)v0.z, (f16)v0.w,
              (f16)v1.x, (f16)v1.y, (f16)v1.z, (f16)v1.w };
  *(f16x8*)(dst + o) = h;
}

#define BARRIER() __builtin_amdgcn_s_barrier()
#define WAIT_VMCNT(n) asm volatile("s_waitcnt vmcnt(" #n ")")

// ---------------------------------------------------------------------------
// GEMM core = r6 structure (2-phase counted-vmcnt, 0 bank conflicts).
// r10 post-mortem (confounded pair, decomposed):
//  - XCD BAND mapping: KEEP. FETCH 270->98.5 MB measured (L2-thrash fix).
//  - nontemporal C stores: REVERT. WRITE 131->240 MB (L2 write-merge bypass
//    on 32B-run f16 stores caused ~2x HBM write amplification, -92us).
// This round isolates the band mapping with normal (write-back) stores.
//
// FUSE=false: C[M,Nc] = tanh(A@B^T + bias) -> f16 (GEMM1).
// FUSE=true : no C write; per-row atomicAdd of sum_col tanh(acc+b)*batchf
//             into rowacc (GEMM2 + rowdot fused).
// ---------------------------------------------------------------------------
template <int K, bool FUSE>
__global__ __launch_bounds__(512, 2)
void gemm256_tanh(const f16* __restrict__ A, const f16* __restrict__ B,
                  const float* __restrict__ bias, f16* __restrict__ C, int Nc,
                  float* __restrict__ rowacc, const float* __restrict__ batchf) {
  extern __shared__ __align__(16) char smem[];
  f16* lds = (f16*)smem;

  const int tid  = threadIdx.x;
  const int lane = tid & 63;
  const int wave = tid >> 6;
  const int wm = (wave >> 2) * 128;
  const int wn = (wave & 3) * 64;
  const int fr = lane & 15;
  const int g  = lane >> 4;

  // XCD band mapping (r10-validated: FETCH 270->98.5 MB): xcd = lin&7
  // (round-robin dispatch, m09); band of nbx/8 row-tiles per XCD; col-major
  // sweep within the band. Resident working set per XCD ~ 8 A-panels (4MB,
  // fits its L2) + B panel.
  const int nbx = gridDim.x;
  const int lin = blockIdx.y * nbx + blockIdx.x;
  const int xcd = lin & 7;
  const int c   = lin >> 3;
  const int rband = nbx >> 3;
  const size_t row0 = (size_t)(xcd * rband + (c % rband)) * 256;
  const size_t col0 = (size_t)(c / rband) * 256;

  // Staging: per unit (kk-half of one operand, 256x32 f16 = 16KB), thread
  // covers 16B slots s = l*512+tid; source chunk pre-swizzled (rule #21):
  // schunk = (s&3) ^ ((s>>3)&3).
  const int schunk = (tid & 3) ^ ((tid >> 3) & 3);
  const f16* Asrc[2]; const f16* Bsrc[2];
  const int sdst0 = tid * 8;
  const int sdst1 = 4096 + tid * 8;
  Asrc[0] = A + (row0 + (tid >> 2)) * (size_t)K + schunk * 8;
  Asrc[1] = A + (row0 + 128 + (tid >> 2)) * (size_t)K + schunk * 8;
  Bsrc[0] = B + (col0 + (tid >> 2)) * (size_t)K + schunk * 8;
  Bsrc[1] = B + (col0 + 128 + (tid >> 2)) * (size_t)K + schunk * 8;

  // LDS f16-offset helpers; read swizzle: slot ^= row bits 1-2 (conflict-free,
  // SQ_LDS_BANK_CONFLICT == 0 measured r3-r9).
  auto aoff = [&](int d, int kk, int m) -> int {
    const int row = wm + m * 16 + fr;
    return d * 32768 + kk * 8192 + row * 32 + (g ^ ((row >> 1) & 3)) * 8;
  };
  auto boff = [&](int d, int kk, int n) -> int {
    const int row = wn + n * 16 + fr;
    return d * 32768 + 16384 + kk * 8192 + row * 32 + (g ^ ((row >> 1) & 3)) * 8;
  };
  auto stage_unit = [&](int j, int db, int kb) {
    const int o = j & 1, kk = j >> 1;
    const int dbase = db * 32768 + o * 16384 + kk * 8192;
    async_ld16((o ? Bsrc[0] : Asrc[0]) + kb + kk * 32, lds + dbase + sdst0);
    async_ld16((o ? Bsrc[1] : Asrc[1]) + kb + kk * 32, lds + dbase + sdst1);
  };

  f32x4 acc[8][4] = {};
  constexpr int NT = K / 64;

  // Prologue: stage tile 0 (units 0..3) into dbuf 0; wait units 0,1.
  stage_unit(0, 0, 0);
  stage_unit(1, 0, 0);
  stage_unit(2, 0, 0);
  stage_unit(3, 0, 0);
  WAIT_VMCNT(4);
  BARRIER();

  for (int t = 0; t < NT; ++t) {
    const int d = t & 1;
    const bool pre = (t + 1) < NT;
    const int kpre = (t + 1) * 64;

    // ---- Phase A: kk0, 32 MFMA ----
    {
      f16x8 bfr[4], afr[8];
#pragma unroll
      for (int n = 0; n < 4; ++n) bfr[n] = *(const f16x8*)(lds + boff(d, 0, n));
#pragma unroll
      for (int i = 0; i < 8; ++i) afr[i] = *(const f16x8*)(lds + aoff(d, 0, i));
      if (pre) { stage_unit(0, d ^ 1, kpre); stage_unit(1, d ^ 1, kpre); }
      BARRIER();
      __builtin_amdgcn_s_setprio(1);
#pragma unroll
      for (int i = 0; i < 8; ++i)
#pragma unroll
        for (int n = 0; n < 4; ++n)
          acc[i][n] = __builtin_amdgcn_mfma_f32_16x16x32_f16(afr[i], bfr[n], acc[i][n], 0, 0, 0);
      __builtin_amdgcn_s_setprio(0);
      if (pre) { WAIT_VMCNT(4); }   // u2,u3(t) landed (in-order retirement)
      else     { WAIT_VMCNT(0); }   // tail drain
      BARRIER();
    }
    // ---- Phase B: kk1, 32 MFMA ----
    {
      f16x8 bfr[4], afr[8];
#pragma unroll
      for (int n = 0; n < 4; ++n) bfr[n] = *(const f16x8*)(lds + boff(d, 1, n));
#pragma unroll
      for (int i = 0; i < 8; ++i) afr[i] = *(const f16x8*)(lds + aoff(d, 1, i));
      if (pre) { stage_unit(2, d ^ 1, kpre); stage_unit(3, d ^ 1, kpre); }
      BARRIER();
      __builtin_amdgcn_s_setprio(1);
#pragma unroll
      for (int i = 0; i < 8; ++i)
#pragma unroll
        for (int n = 0; n < 4; ++n)
          acc[i][n] = __builtin_amdgcn_mfma_f32_16x16x32_f16(afr[i], bfr[n], acc[i][n], 0, 0, 0);
      __builtin_amdgcn_s_setprio(0);
      if (pre) { WAIT_VMCNT(4); }   // u0,u1(t+1) landed
      BARRIER();
    }
  }

  // Epilogue; C/D map: col=lane&15, row=(lane>>4)*4+reg [m89-verified]
  if constexpr (!FUSE) {
#pragma unroll
    for (int m = 0; m < 8; ++m) {
#pragma unroll
      for (int n = 0; n < 4; ++n) {
        const size_t gcol = col0 + wn + n * 16 + fr;
        const float bia = bias[gcol];
        f16* Cp = C + (row0 + wm + m * 16 + g * 4) * (size_t)Nc + gcol;
#pragma unroll
        for (int r = 0; r < 4; ++r)
          Cp[(size_t)r * Nc] = (f16)fast_tanh(acc[m][n][r] + bia);
      }
    }
  } else {
    // Fused rowdot: reduce over fr (16 lanes, shfl_xor 1/2/4/8 within the
    // g-group), then 1 atomicAdd per row per wave.
    float rsum[8][4];
#pragma unroll
    for (int m = 0; m < 8; ++m)
#pragma unroll
      for (int r = 0; r < 4; ++r) rsum[m][r] = 0.f;
#pragma unroll
    for (int m = 0; m < 8; ++m) {
#pragma unroll
      for (int n = 0; n < 4; ++n) {
        const size_t gcol = col0 + wn + n * 16 + fr;
        const float bia = bias[gcol];
        const float* bp = batchf + (row0 + wm + m * 16 + g * 4) * DMODEL + gcol;
#pragma unroll
        for (int r = 0; r < 4; ++r)
          rsum[m][r] += fast_tanh(acc[m][n][r] + bia) * bp[(size_t)r * DMODEL];
      }
    }
#pragma unroll
    for (int m = 0; m < 8; ++m) {
#pragma unroll
      for (int r = 0; r < 4; ++r) {
        float s = rsum[m][r];
        s += __shfl_xor(s, 1, 64);
        s += __shfl_xor(s, 2, 64);
        s += __shfl_xor(s, 4, 64);
        s += __shfl_xor(s, 8, 64);
        if (fr == 0)
          atomicAdd(&rowacc[row0 + wm + m * 16 + g * 4 + r], s);
      }
    }
  }
}

// out[row] = sigmoid(rowacc[row])
__global__ void sigmoid_rows(const float* __restrict__ rowacc, float* __restrict__ out) {
  const int i = blockIdx.x * blockDim.x + threadIdx.x;
  out[i] = 1.0f / (1.0f + __expf(-rowacc[i]));
}

extern "C" void kernel_launch(void* const* d_in, const int* in_sizes, int n_in,
                              void* d_out, int out_size, void* d_ws, size_t ws_size,
                              hipStream_t stream) {
  const float* batch = (const float*)d_in[0];
  const float* W1    = (const float*)d_in[1];
  const float* b1    = (const float*)d_in[2];
  const float* W2    = (const float*)d_in[3];
  const float* b2    = (const float*)d_in[4];
  float* out = (float*)d_out;

  char* ws = (char*)d_ws;
  f16* batch_h  = (f16*)ws;   ws += (size_t)N_ROWS * DMODEL * sizeof(f16);  //  32 MB
  f16* W1_h     = (f16*)ws;   ws += (size_t)DFF * DMODEL * sizeof(f16);     //   8 MB
  f16* W2_h     = (f16*)ws;   ws += (size_t)DMODEL * DFF * sizeof(f16);     //   8 MB
  f16* inner_h  = (f16*)ws;   ws += (size_t)N_ROWS * DFF * sizeof(f16);     // 128 MB
  float* rowacc = (float*)ws; ws += (size_t)N_ROWS * sizeof(float);         //  64 KB

  static bool attr_set = false;
  if (!attr_set) {
    (void)hipFuncSetAttribute((const void*)gemm256_tanh<DMODEL, false>,
                              hipFuncAttributeMaxDynamicSharedMemorySize, 131072);
    (void)hipFuncSetAttribute((const void*)gemm256_tanh<DFF, true>,
                              hipFuncAttributeMaxDynamicSharedMemorySize, 131072);
    attr_set = true;
  }

  // merged casts + rowacc zero
  const size_t nb = (size_t)N_ROWS * DMODEL;
  const size_t nw = (size_t)DFF * DMODEL;
  const int total_thr = (int)((nb + 2 * nw) / 8 + N_ROWS / 8);
  cast_and_zero<<<total_thr / 256, 256, 0, stream>>>(batch, batch_h, W1, W1_h,
                                                     W2, W2_h, rowacc);

  dim3 g1(N_ROWS / 256, DFF / 256);     // (64, 16)
  gemm256_tanh<DMODEL, false><<<g1, 512, 131072, stream>>>(
      batch_h, W1_h, b1, inner_h, DFF, nullptr, nullptr);
  dim3 g2(N_ROWS / 256, DMODEL / 256);  // (64, 4)
  gemm256_tanh<DFF, true><<<g2, 512, 131072, stream>>>(
      inner_h, W2_h, b2, nullptr, DMODEL, rowacc, batch);

  sigmoid_rows<<<N_ROWS / 256, 256, 0, stream>>>(rowacc, out);
}